// Round 9
// baseline (809.025 us; speedup 1.0000x reference)
//
#include <hip/hip_runtime.h>
#include <math.h>

#define BATCH 8
#define NPTS 4096
#define CHAN 128
#define KNN 16
#define NGRP (NPTS / 16)        // 256 groups of 16 x-sorted points
#define RSPLIT 4
#define RCHUNK (NPTS / RSPLIT)
#define PRUNE_EPS 1e-3f         // >= 50x the fp32 d2-formula rounding bound

typedef unsigned long long u64;

// Monotone key: ascending u64 == (d2 ascending, ORIGINAL idx ascending).
// Ties in d2 break toward lower original index == lax.top_k stable order.
__device__ __forceinline__ u64 pack_key(float d2, int idx) {
  unsigned b = __float_as_uint(d2);
  b ^= (unsigned)((int)b >> 31) | 0x80000000u;
  return ((u64)b << 32) | (unsigned)idx;
}
// Inverse of the high-word map (sentinel 0xFFFFFFFF -> NaN -> never prunes).
__device__ __forceinline__ float unmap_hi(unsigned b) {
  unsigned r = (b & 0x80000000u) ? (b ^ 0x80000000u) : ~b;
  return __uint_as_float(r);
}

__device__ __forceinline__ void ce_asc(u64& x, u64& y) {
  bool sw = y < x;
  u64 lo = sw ? y : x;
  u64 hi = sw ? x : y;
  x = lo; y = hi;
}

__device__ __forceinline__ void bitonic_sort16(u64 a[16]) {
#pragma unroll
  for (int k = 2; k <= 16; k <<= 1) {
#pragma unroll
    for (int j = k >> 1; j > 0; j >>= 1) {
#pragma unroll
      for (int i = 0; i < 16; ++i) {
        int l = i ^ j;
        if (l > i) {
          if ((i & k) == 0) ce_asc(a[i], a[l]);
          else              ce_asc(a[l], a[i]);
        }
      }
    }
  }
}

// T,A sorted asc -> T = lowest-16 of union, sorted. 16 min + 32 CE.
__device__ __forceinline__ void merge_keep16(u64 T[16], const u64 A[16]) {
  u64 nt[16];
#pragma unroll
  for (int i = 0; i < 16; ++i) {
    u64 a = A[15 - i];
    nt[i] = (a < T[i]) ? a : T[i];
  }
#pragma unroll
  for (int j = 8; j > 0; j >>= 1) {
#pragma unroll
    for (int i = 0; i < 16; ++i) {
      int l = i ^ j;
      if (l > i) ce_asc(nt[i], nt[l]);
    }
  }
#pragma unroll
  for (int i = 0; i < 16; ++i) T[i] = nt[i];
}

// ---------------------------------------------------------------------------
// Zero both count arrays (xcnt ∪ cnt = 2*B*N ints, contiguous).
// ---------------------------------------------------------------------------
__global__ __launch_bounds__(256) void zero_kernel(int* __restrict__ p) {
  p[blockIdx.x * 256 + threadIdx.x] = 0;
}

// ---------------------------------------------------------------------------
// Split x-rank count: rank(n) = #{m: x_m<x_n or (x_m==x_n and m<n)}.
// Any bijection works for correctness; x-sort gives spatial coherence.
// grid: B*16*RSPLIT = 512 blocks.
// ---------------------------------------------------------------------------
__global__ __launch_bounds__(256) void xcnt_partial_kernel(
    const float* __restrict__ x, int* __restrict__ xcnt) {
  const int s = blockIdx.x % RSPLIT;
  const int ntile = (blockIdx.x / RSPLIT) % (NPTS / 256);
  const int b = blockIdx.x / (RSPLIT * (NPTS / 256));
  __shared__ float xs[RCHUNK];
  const float* xb = x + (size_t)b * 3 * NPTS;
  for (int i = threadIdx.x; i < RCHUNK; i += 256)
    xs[i] = xb[s * RCHUNK + i];
  const int n = ntile * 256 + threadIdx.x;
  const float xn = xb[n];
  __syncthreads();
  int c = 0;
#pragma unroll 8
  for (int mm = 0; mm < RCHUNK; ++mm) {
    float xm = xs[mm];
    int gm = s * RCHUNK + mm;
    c += (xm < xn) || (xm == xn && gm < n);
  }
  atomicAdd(&xcnt[(size_t)b * NPTS + n], c);
}

// ---------------------------------------------------------------------------
// Scatter into x-sorted order; .w carries the ORIGINAL index bits.
// ---------------------------------------------------------------------------
__global__ __launch_bounds__(256) void build_sorted_kernel(
    const float* __restrict__ x, const int* __restrict__ xcnt,
    float4* __restrict__ sorted4) {
  const int t = blockIdx.x * 256 + threadIdx.x;  // over B*N
  const int b = t / NPTS;
  const int n = t % NPTS;
  const float* xb = x + (size_t)b * 3 * NPTS;
  int r = xcnt[t];
  sorted4[(size_t)b * NPTS + r] =
      make_float4(xb[n], xb[NPTS + n], xb[2 * NPTS + n], __int_as_float(n));
}

// ---------------------------------------------------------------------------
// Per-group [16 sorted points] min/max x.
// ---------------------------------------------------------------------------
__global__ __launch_bounds__(256) void aabb_kernel(
    const float4* __restrict__ sorted4, float* __restrict__ gmin,
    float* __restrict__ gmax) {
  const int t = blockIdx.x * 256 + threadIdx.x;  // over B*NGRP = 2048
  const int b = t / NGRP;
  const int g = t % NGRP;
  const float4* p = sorted4 + (size_t)b * NPTS + g * 16;
  float mn = p[0].x, mx = p[0].x;
#pragma unroll
  for (int i = 1; i < 16; ++i) {
    float v = p[i].x;
    mn = fminf(mn, v);
    mx = fmaxf(mx, v);
  }
  gmin[t] = mn;
  gmax[t] = mx;
}

// ---------------------------------------------------------------------------
// Fused KNN + score. grid: B*(N/128)=256 blocks, 128 thr. LDS: whole batch
// (64 KB) + group x-extents. Wave = 64 x-consecutive queries. GLOBAL prune
// threshold (round 8 failed because split-local thresholds barely prune):
// evaluate wave's own 4 groups, then sweep right/left; x-sorted => group
// min-x-dist is MONOTONE in sweep direction => wave-uniform break when all
// lanes prove dx^2 > thr+eps is exact-conservative (rounding <=~5e-5 << eps).
// Keys carry original indices -> tie-break == lax.top_k. Epilogue computes
// the numpy-pairwise fp32 score (bit-exact, validated round 2).
// ---------------------------------------------------------------------------
__global__ __attribute__((amdgpu_waves_per_eu(1, 2)))
__launch_bounds__(128) void knn_score_kernel(
    const float* __restrict__ x, const float4* __restrict__ sorted4,
    const float* __restrict__ gmin, const float* __restrict__ gmax,
    float* __restrict__ score) {
  const int b = blockIdx.x / (NPTS / 128);
  const int tile = blockIdx.x % (NPTS / 128);

  __shared__ float4 sp[NPTS];        // 64 KB
  __shared__ float gmn[NGRP], gmx[NGRP];

  const float4* sb = sorted4 + (size_t)b * NPTS;
  for (int i = threadIdx.x; i < NPTS; i += 128) sp[i] = sb[i];
  for (int i = threadIdx.x; i < NGRP; i += 128) {
    gmn[i] = gmin[b * NGRP + i];
    gmx[i] = gmax[b * NGRP + i];
  }
  __syncthreads();

  const int pos = tile * 128 + threadIdx.x;  // sorted position of my query
  const float4 p4 = sp[pos];
  const float ppx = p4.x, ppy = p4.y, ppz = p4.z;
  const float psq = __fadd_rn(
      __fadd_rn(__fmul_rn(ppx, ppx), __fmul_rn(ppy, ppy)),
      __fmul_rn(ppz, ppz));

  u64 T[16];
#pragma unroll
  for (int i = 0; i < 16; ++i) T[i] = ~0ull;

#define EVAL_GROUP(G)                                                        \
  do {                                                                       \
    u64 A[16];                                                               \
    _Pragma("unroll") for (int t = 0; t < 16; ++t) {                         \
      float4 q = sp[(G) * 16 + t];                                           \
      float qsq = __fadd_rn(                                                 \
          __fadd_rn(__fmul_rn(q.x, q.x), __fmul_rn(q.y, q.y)),               \
          __fmul_rn(q.z, q.z));                                              \
      float inner = __fadd_rn(                                               \
          __fadd_rn(__fmul_rn(ppx, q.x), __fmul_rn(ppy, q.y)),               \
          __fmul_rn(ppz, q.z));                                              \
      float d2 = __fsub_rn(__fadd_rn(psq, qsq), __fmul_rn(2.0f, inner));     \
      A[t] = pack_key(d2, __float_as_int(q.w));                              \
    }                                                                        \
    bitonic_sort16(A);                                                       \
    merge_keep16(T, A);                                                      \
  } while (0)

  // wave = 64 consecutive sorted queries = exactly 4 groups
  const int wbase = (pos & ~63) / 16;
#pragma unroll
  for (int gg = 0; gg < 4; ++gg) EVAL_GROUP(wbase + gg);
  float thr = unmap_hi((unsigned)(T[15] >> 32));

  // right sweep: dx = gmn[g]-ppx >= 0 for all lanes, monotone in g
  for (int g = wbase + 4; g < NGRP; ++g) {
    float dx = gmn[g] - ppx;
    bool needed = !(dx * dx > thr + PRUNE_EPS);
    if (!__any(needed)) break;
    EVAL_GROUP(g);
    thr = unmap_hi((unsigned)(T[15] >> 32));
  }
  // left sweep: dx = ppx-gmx[g] >= 0 for all lanes, monotone as g decreases
  for (int g = wbase - 1; g >= 0; --g) {
    float dx = ppx - gmx[g];
    bool needed = !(dx * dx > thr + PRUNE_EPS);
    if (!__any(needed)) break;
    EVAL_GROUP(g);
    thr = unmap_hi((unsigned)(T[15] >> 32));
  }
#undef EVAL_GROUP

  // Epilogue: numpy fp32 pairwise score over neighbors in rank order.
  const float* xb = x + (size_t)b * 3 * NPTS;
  float nx[KNN], ny[KNN], nz[KNN];
#pragma unroll
  for (int j = 0; j < KNN; ++j) {
    int idx = (int)(unsigned)T[j];
    nx[j] = xb[idx];
    ny[j] = xb[NPTS + idx];
    nz[j] = xb[2 * NPTS + idx];
  }
  float P[3];
#pragma unroll
  for (int d = 0; d < 3; ++d) {
    const float pc = (d == 0) ? ppx : ((d == 1) ? ppy : ppz);
    float r[8];
#pragma unroll
    for (int j = 0; j < 8; ++j) {
      float c0 = (d == 0) ? nx[j] : ((d == 1) ? ny[j] : nz[j]);
      float c1 = (d == 0) ? nx[j + 8] : ((d == 1) ? ny[j + 8] : nz[j + 8]);
      float e0 = __fsub_rn(c0, pc);
      float e1 = __fsub_rn(c1, pc);
      r[j] = __fadd_rn(__fmul_rn(e0, e0), __fmul_rn(e1, e1));
    }
    float t0 = __fadd_rn(r[0], r[1]);
    float t1 = __fadd_rn(r[2], r[3]);
    float t2 = __fadd_rn(r[4], r[5]);
    float t3 = __fadd_rn(r[6], r[7]);
    P[d] = __fadd_rn(__fadd_rn(t0, t1), __fadd_rn(t2, t3));
  }
  const int orig = __float_as_int(p4.w);
  score[(size_t)b * NPTS + orig] =
      __fadd_rn(__fadd_rn(P[0], P[1]), P[2]);
}

// ---------------------------------------------------------------------------
// Rank pipeline (original-index domain; validated rounds 2-7).
// ---------------------------------------------------------------------------
__global__ __launch_bounds__(256) void rank_partial_kernel(
    const float* __restrict__ score, int* __restrict__ cnt) {
  const int s = blockIdx.x % RSPLIT;
  const int ntile = (blockIdx.x / RSPLIT) % (NPTS / 256);
  const int b = blockIdx.x / (RSPLIT * (NPTS / 256));
  __shared__ float ss[RCHUNK];
  const float* sb = score + (size_t)b * NPTS;
  for (int i = threadIdx.x; i < RCHUNK; i += 256)
    ss[i] = sb[s * RCHUNK + i];
  const int n = ntile * 256 + threadIdx.x;
  const float sn = sb[n];
  __syncthreads();
  int c = 0;
#pragma unroll 8
  for (int mm = 0; mm < RCHUNK; ++mm) {
    float sm = ss[mm];
    int gm = s * RCHUNK + mm;
    c += (sm > sn) || (sm == sn && gm < n);
  }
  atomicAdd(&cnt[(size_t)b * NPTS + n], c);
}

__global__ __launch_bounds__(256) void rank_scatter_kernel(
    const int* __restrict__ cnt, int* __restrict__ sel, int npts) {
  int t = blockIdx.x * 256 + threadIdx.x;
  int b = t / NPTS;
  int n = t % NPTS;
  int c = cnt[t];
  if (c < npts) sel[(size_t)b * npts + c] = n;
}

__global__ __launch_bounds__(256) void gather_kernel(
    const float* __restrict__ x, const float* __restrict__ y,
    const int* __restrict__ sel, float* __restrict__ out, int npts,
    int total0, int total) {
  int tid = blockIdx.x * blockDim.x + threadIdx.x;
  if (tid >= total) return;
  if (tid < total0) {
    int j = tid % npts;
    int rest = tid / npts;
    int d = rest % 3;
    int b = rest / 3;
    int src = sel[b * npts + j];
    out[tid] = x[((size_t)b * 3 + d) * NPTS + src];
  } else {
    int t = tid - total0;
    int j = t % npts;
    int rest = t / npts;
    int c = rest % CHAN;
    int b = rest / CHAN;
    int src = sel[b * npts + j];
    out[tid] = y[((size_t)b * CHAN + c) * NPTS + src];
  }
}

extern "C" void kernel_launch(void* const* d_in, const int* in_sizes, int n_in,
                              void* d_out, int out_size, void* d_ws,
                              size_t ws_size, hipStream_t stream) {
  const float* x = (const float*)d_in[0];
  const float* y = (const float*)d_in[1];
  float* out = (float*)d_out;

  const int npts = out_size / (BATCH * (3 + CHAN));

  // workspace layout:
  char* w = (char*)d_ws;
  float4* sorted4 = (float4*)w;              // 512 KB
  w += sizeof(float4) * (size_t)BATCH * NPTS;
  float* gmin = (float*)w;                   // 8 KB
  w += sizeof(float) * (size_t)BATCH * NGRP;
  float* gmax = (float*)w;                   // 8 KB
  w += sizeof(float) * (size_t)BATCH * NGRP;
  // xcnt (early, int) aliases score (late, float): disjoint lifetimes.
  int* xcnt = (int*)w;
  float* score = (float*)w;                  // 128 KB
  w += sizeof(float) * (size_t)BATCH * NPTS;
  int* cnt = (int*)w;                        // 128 KB (contiguous after xcnt)
  w += sizeof(int) * (size_t)BATCH * NPTS;
  int* sel = (int*)w;                        // 64 KB

  // zero xcnt + cnt in one go (contiguous 2*B*N ints)
  zero_kernel<<<2 * BATCH * NPTS / 256, 256, 0, stream>>>(xcnt);
  xcnt_partial_kernel<<<BATCH * (NPTS / 256) * RSPLIT, 256, 0, stream>>>(
      x, xcnt);
  build_sorted_kernel<<<BATCH * NPTS / 256, 256, 0, stream>>>(
      x, xcnt, sorted4);
  aabb_kernel<<<BATCH * NGRP / 256, 256, 0, stream>>>(sorted4, gmin, gmax);
  knn_score_kernel<<<BATCH * (NPTS / 128), 128, 0, stream>>>(
      x, sorted4, gmin, gmax, score);
  rank_partial_kernel<<<BATCH * (NPTS / 256) * RSPLIT, 256, 0, stream>>>(
      score, cnt);
  rank_scatter_kernel<<<BATCH * NPTS / 256, 256, 0, stream>>>(cnt, sel, npts);

  const int total0 = BATCH * 3 * npts;
  gather_kernel<<<(out_size + 255) / 256, 256, 0, stream>>>(
      x, y, sel, out, npts, total0, out_size);
}